// Round 4
// baseline (497.588 us; speedup 1.0000x reference)
//
#include <hip/hip_runtime.h>

#define N 8192
#define DIN 128
#define DH 48
#define MT 128           // rows per k_gat block
#define KC 64            // j-chunk
#define PSTR 72          // pS row stride in halves: 144 B -> 2-way bank aliasing (free)
#define NSPLIT 16
#define JSPAN (N / NSPLIT)   // 512
#define NCHUNK (JSPAN / KC)  // 8
#define HSTR 49          // hacc row stride (48 dims + lsum)
#define RB 32            // rows per k_mlp block

typedef _Float16 half8 __attribute__((ext_vector_type(8)));
typedef float f32x4 __attribute__((ext_vector_type(4)));

// ---------------- zero hacc (ws is poisoned 0xAA before every call)
__global__ __launch_bounds__(256) void k_zero(float* __restrict__ hacc) {
    int i = blockIdx.x * 256 + threadIdx.x;
    if (i < N * HSTR) hacc[i] = 0.f;
}

// ---------------- Kernel 1a: Wh = x @ Wgat^T  [8192,128]x[48,128] -> [8192,48]
__global__ __launch_bounds__(256) void k_wh(const float* __restrict__ x,
                                            const float* __restrict__ Wg,
                                            float* __restrict__ Wh) {
    __shared__ float wT[DIN * DH];  // wT[k*DH + c] = Wg[c*DIN + k]
    int t = threadIdx.x;
    for (int e = t; e < DIN * DH; e += 256) {
        int c = e / DIN, k = e % DIN;
        wT[k * DH + c] = Wg[e];
    }
    __syncthreads();
    int o = blockIdx.x * 256 + t;
    int r = o / DH, c = o % DH;
    const float4* xr = (const float4*)(x + (size_t)r * DIN);
    float acc = 0.f;
    #pragma unroll 8
    for (int k4 = 0; k4 < DIN / 4; ++k4) {
        float4 xv = xr[k4];
        int kb = k4 * 4;
        acc += xv.x * wT[(kb + 0) * DH + c];
        acc += xv.y * wT[(kb + 1) * DH + c];
        acc += xv.z * wT[(kb + 2) * DH + c];
        acc += xv.w * wT[(kb + 3) * DH + c];
    }
    Wh[o] = acc;
}

// ---------------- Kernel 1b: s = Wh @ a^T
__global__ __launch_bounds__(256) void k_s(const float* __restrict__ Wh,
                                           const float* __restrict__ a,
                                           float* __restrict__ s) {
    int r = blockIdx.x * 256 + threadIdx.x;
    const float4* wr = (const float4*)(Wh + (size_t)r * DH);
    const float4* av = (const float4*)a;
    float acc = 0.f;
    #pragma unroll
    for (int k4 = 0; k4 < DH / 4; ++k4) {
        float4 w = wr[k4]; float4 aa = av[k4];
        acc += w.x * aa.x + w.y * aa.y + w.z * aa.z + w.w * aa.w;
    }
    s[r] = acc;
}

// ---------------- Kernel 1c: WhT16[c][r] = (f16)Wh[r][c]  (B operand for k_gat)
__global__ __launch_bounds__(256) void k_tr(const float* __restrict__ Wh,
                                            _Float16* __restrict__ WhT) {
    __shared__ _Float16 tile[DH][72];   // padded
    int t = threadIdx.x;
    int r0 = blockIdx.x * 64;
    for (int e = t; e < 64 * DH; e += 256) {
        int r = e / DH, c = e % DH;
        tile[c][r] = (_Float16)Wh[(size_t)(r0 + r) * DH + c];
    }
    __syncthreads();
    for (int u = t; u < DH * 8; u += 256) {
        int c = u >> 3, g = u & 7;
        *(half8*)&WhT[(size_t)c * N + r0 + g * 8] = *(const half8*)&tile[c][g * 8];
    }
}

// ---------------- Kernel 2: fused masked-softmax attention, f16 MFMA.
// e = lrelu(s_i+s_j) bounded -> softmax without max-subtraction; masked -> 0.
// Per block: 128 rows x 512 j (one of 16 J-splits). Per 64-j chunk:
//   prefetch adj (16x int2/thread) + B-frags (global L2, WhT16) -> compute
//   p into pS (f16) -> barrier -> 16 MFMA/wave. Softmax denom = ones-column
//   B-frag (compile-time constant, N-tile 3). Partials atomicAdd into hacc.
__global__ __launch_bounds__(256, 4) void k_gat(const int* __restrict__ adj,
                                                const _Float16* __restrict__ WhT,
                                                const float* __restrict__ s,
                                                float* __restrict__ hacc) {
    __shared__ _Float16 pS[MT][PSTR];   // A: P[row][j]
    __shared__ float sRow[MT];
    int t = threadIdx.x;
    int tile = blockIdx.x & 63;        // 64 row tiles of 128
    int split = blockIdx.x >> 6;       // 0..15
    int i0 = tile * MT;
    int jbase = split * JSPAN;

    if (t < MT) sRow[t] = s[i0 + t];

    int lane = t & 63, w = t >> 6;
    int ln16 = lane & 15, kq = lane >> 4;   // MFMA lane decomposition
    int jp = t & 31, rg = t >> 5;           // phase A: j-pair, row group (16 rows)

    // constant B-frag for N-tile 3: column 48 = ones (softmax denom), rest 0
    half8 bc;
    {
        _Float16 v = (ln16 == 0) ? (_Float16)1.0f : (_Float16)0.0f;
        #pragma unroll
        for (int i = 0; i < 8; ++i) bc[i] = v;
    }

    f32x4 acc[2][4];
    #pragma unroll
    for (int m = 0; m < 2; ++m)
        #pragma unroll
        for (int n = 0; n < 4; ++n) acc[m][n] = (f32x4){0.f, 0.f, 0.f, 0.f};

    __syncthreads();

    for (int chunk = 0; chunk < NCHUNK; ++chunk) {
        int j0 = jbase + chunk * KC;
        // ---- prefetch adj (coalesced along j) and B-frags (global, L2-resident)
        int2 av[16];
        {
            const int* abase = adj + (size_t)(i0 + rg * 16) * N + j0 + 2 * jp;
            #pragma unroll
            for (int it = 0; it < 16; ++it)
                av[it] = *(const int2*)(abase + (size_t)it * N);
        }
        half8 bfr[2][3];
        #pragma unroll
        for (int kt = 0; kt < 2; ++kt)
            #pragma unroll
            for (int nt = 0; nt < 3; ++nt)
                bfr[kt][nt] = *(const half8*)&WhT[(size_t)(nt * 16 + ln16) * N
                                                  + j0 + kt * 32 + kq * 8];
        // ---- phase A: p (f16) for 128 rows x 64 j
        {
            float2 sj = *(const float2*)(s + j0 + 2 * jp);
            #pragma unroll
            for (int it = 0; it < 16; ++it) {
                int r = rg * 16 + it;
                float e0 = sRow[r] + sj.x;
                float e1 = sRow[r] + sj.y;
                e0 = fmaxf(e0, 0.2f * e0);              // LeakyReLU(0.2)
                e1 = fmaxf(e1, 0.2f * e1);
                float p0 = av[it].x ? __expf(e0) : 0.f; // masked -> exact 0
                float p1 = av[it].y ? __expf(e1) : 0.f;
                union { _Float16 h[2]; unsigned u; } pk;
                pk.h[0] = (_Float16)p0;
                pk.h[1] = (_Float16)p1;
                *(unsigned*)&pS[r][2 * jp] = pk.u;
            }
        }
        __syncthreads();
        // ---- MFMA: wave w owns M-tiles 2w..2w+1, 4 N-tiles (3 = ones col)
        {
            int m0 = w * 32;
            #pragma unroll
            for (int kt = 0; kt < 2; ++kt) {
                int kk = kt * 32 + kq * 8;
                #pragma unroll
                for (int mtl = 0; mtl < 2; ++mtl) {
                    half8 a = *(const half8*)&pS[m0 + mtl * 16 + ln16][kk];
                    acc[mtl][0] = __builtin_amdgcn_mfma_f32_16x16x32_f16(a, bfr[kt][0], acc[mtl][0], 0, 0, 0);
                    acc[mtl][1] = __builtin_amdgcn_mfma_f32_16x16x32_f16(a, bfr[kt][1], acc[mtl][1], 0, 0, 0);
                    acc[mtl][2] = __builtin_amdgcn_mfma_f32_16x16x32_f16(a, bfr[kt][2], acc[mtl][2], 0, 0, 0);
                    acc[mtl][3] = __builtin_amdgcn_mfma_f32_16x16x32_f16(a, bc,         acc[mtl][3], 0, 0, 0);
                }
            }
        }
        __syncthreads();
    }
    // ---- epilogue: C/D layout col=lane&15, row=kq*4+reg; atomic split-reduce
    #pragma unroll
    for (int mtl = 0; mtl < 2; ++mtl) {
        int rbase = i0 + w * 32 + mtl * 16 + kq * 4;
        #pragma unroll
        for (int nt = 0; nt < 4; ++nt) {
            int col = nt * 16 + ln16;
            if (nt == 3 && ln16 != 0) continue;   // only col 48 (lsum) useful
            #pragma unroll
            for (int reg = 0; reg < 4; ++reg)
                atomicAdd(&hacc[(size_t)(rbase + reg) * HSTR + col], acc[mtl][nt][reg]);
        }
    }
}

// ---------------- Kernel 3: LayerNorm + MLP 48->256->128->32 (register-tiled)
__global__ __launch_bounds__(256) void k_mlp(const float* __restrict__ hacc,
                                             const float* __restrict__ gamma,
                                             const float* __restrict__ beta,
                                             const float* __restrict__ W1, const float* __restrict__ b1,
                                             const float* __restrict__ W2, const float* __restrict__ b2,
                                             const float* __restrict__ W3, const float* __restrict__ b3,
                                             float* __restrict__ out) {
    __shared__ float hs[RB * HSTR];
    __shared__ float hN[RB * DH];
    __shared__ float h1[RB * 256];
    __shared__ float h2[RB * 128];
    int t = threadIdx.x;
    int r0 = blockIdx.x * RB;

    for (int e = t; e < RB * HSTR; e += 256)
        hs[e] = hacc[(size_t)r0 * HSTR + e];
    __syncthreads();

    // LayerNorm (two-pass), h' = acc / l
    if (t < RB) {
        float invl = 1.f / hs[t * HSTR + 48];
        float sum = 0.f;
        for (int d = 0; d < DH; ++d) sum += hs[t * HSTR + d];
        float mean = sum * invl * (1.f / DH);
        float var = 0.f;
        for (int d = 0; d < DH; ++d) {
            float dv = hs[t * HSTR + d] * invl - mean;
            var += dv * dv;
        }
        var *= (1.f / DH);
        float rs = rsqrtf(var + 1e-5f);
        for (int d = 0; d < DH; ++d) {
            float hv = (hs[t * HSTR + d] * invl - mean) * rs;
            hN[t * DH + d] = hv * gamma[d] + beta[d];
        }
    }
    __syncthreads();

    // MLP1: 48 -> 256; thread = 2 cols x 16 rows, W1 cols in VGPRs
    {
        int c0 = (t & 127) * 2, c1 = c0 + 1;
        int rbeg = (t >> 7) * 16;
        float4 wa[12], wb[12];
        const float4* wr0 = (const float4*)(W1 + c0 * DH);
        const float4* wr1 = (const float4*)(W1 + c1 * DH);
        #pragma unroll
        for (int k4 = 0; k4 < 12; ++k4) { wa[k4] = wr0[k4]; wb[k4] = wr1[k4]; }
        float ba = b1[c0], bb = b1[c1];
        for (int r = rbeg; r < rbeg + 16; ++r) {
            const float4* hv4 = (const float4*)&hN[r * DH];
            float a0 = ba, a1 = bb;
            #pragma unroll
            for (int k4 = 0; k4 < 12; ++k4) {
                float4 hv = hv4[k4];
                a0 += hv.x * wa[k4].x + hv.y * wa[k4].y + hv.z * wa[k4].z + hv.w * wa[k4].w;
                a1 += hv.x * wb[k4].x + hv.y * wb[k4].y + hv.z * wb[k4].z + hv.w * wb[k4].w;
            }
            h1[r * 256 + c0] = fmaxf(a0, 0.f);
            h1[r * 256 + c1] = fmaxf(a1, 0.f);
        }
    }
    __syncthreads();

    // MLP2: 256 -> 128; thread = 4 cols x 4 rows (16 FMA per LDS b128)
    {
        int c4 = (t & 31) * 4;
        int rr0 = (t >> 5) * 4;
        float a[4][4];
        #pragma unroll
        for (int rr = 0; rr < 4; ++rr)
            #pragma unroll
            for (int cc = 0; cc < 4; ++cc) a[rr][cc] = 0.f;
        for (int k4 = 0; k4 < 64; ++k4) {
            float4 h[4], wv[4];
            #pragma unroll
            for (int rr = 0; rr < 4; ++rr)
                h[rr] = *(const float4*)&h1[(rr0 + rr) * 256 + 4 * k4];
            #pragma unroll
            for (int cc = 0; cc < 4; ++cc)
                wv[cc] = *(const float4*)&W2[(size_t)(c4 + cc) * 256 + 4 * k4];
            #pragma unroll
            for (int rr = 0; rr < 4; ++rr)
                #pragma unroll
                for (int cc = 0; cc < 4; ++cc)
                    a[rr][cc] += h[rr].x * wv[cc].x + h[rr].y * wv[cc].y
                               + h[rr].z * wv[cc].z + h[rr].w * wv[cc].w;
        }
        #pragma unroll
        for (int rr = 0; rr < 4; ++rr)
            #pragma unroll
            for (int cc = 0; cc < 4; ++cc)
                h2[(rr0 + rr) * 128 + c4 + cc] = fmaxf(a[rr][cc] + b2[c4 + cc], 0.f);
    }
    __syncthreads();

    // MLP3: 128 -> 32; thread = 1 col x 4 rows
    {
        int c = t & 31;
        int rr0 = (t >> 5) * 4;
        float a[4];
        float bias = b3[c];
        #pragma unroll
        for (int rr = 0; rr < 4; ++rr) a[rr] = bias;
        const float4* wrow = (const float4*)(W3 + c * 128);
        for (int k4 = 0; k4 < 32; ++k4) {
            float4 wv = wrow[k4];
            #pragma unroll
            for (int rr = 0; rr < 4; ++rr) {
                float4 hv = *(const float4*)&h2[(rr0 + rr) * 128 + 4 * k4];
                a[rr] += wv.x * hv.x + wv.y * hv.y + wv.z * hv.z + wv.w * hv.w;
            }
        }
        #pragma unroll
        for (int rr = 0; rr < 4; ++rr)
            out[(size_t)(r0 + rr0 + rr) * 32 + c] = a[rr];
    }
}

extern "C" void kernel_launch(void* const* d_in, const int* in_sizes, int n_in,
                              void* d_out, int out_size, void* d_ws, size_t ws_size,
                              hipStream_t stream) {
    const float* x     = (const float*)d_in[0];
    const int*   adj   = (const int*)d_in[1];
    const float* Wg    = (const float*)d_in[2];
    const float* a     = (const float*)d_in[3];
    const float* gamma = (const float*)d_in[4];
    const float* beta  = (const float*)d_in[5];
    const float* W1    = (const float*)d_in[6];
    const float* b1    = (const float*)d_in[7];
    const float* W2    = (const float*)d_in[8];
    const float* b2    = (const float*)d_in[9];
    const float* W3    = (const float*)d_in[10];
    const float* b3    = (const float*)d_in[11];
    float* out = (float*)d_out;

    float* ws = (float*)d_ws;
    float*     Wh   = ws;                                   // 393216 f32
    float*     s    = ws + (size_t)N * DH;                  // 8192 f32
    _Float16*  WhT  = (_Float16*)(ws + (size_t)N * DH + N); // 393216 f16
    float*     hacc = ws + (size_t)N * DH + N + (size_t)N * DH / 2; // 401408 f32

    k_zero<<<(N * HSTR + 255) / 256, 256, 0, stream>>>(hacc);
    k_wh<<<N * DH / 256, 256, 0, stream>>>(x, Wg, Wh);
    k_s<<<N / 256, 256, 0, stream>>>(Wh, a, s);
    k_tr<<<N / 64, 256, 0, stream>>>(Wh, WhT);
    k_gat<<<64 * NSPLIT, 256, 0, stream>>>(adj, WhT, s, hacc);
    k_mlp<<<N / RB, 256, 0, stream>>>(hacc, gamma, beta, W1, b1, W2, b2, W3, b3, out);
}

// Round 5
// 481.679 us; speedup vs baseline: 1.0330x; 1.0330x over previous
//
#include <hip/hip_runtime.h>

#define N 8192
#define DIN 128
#define DH 48
#define MT 128           // rows per k_gat block
#define KC 64            // j-chunk
#define PSTR 72          // LDS row stride in halves: 144 B -> 2-way bank aliasing (free)
#define NSPLIT 16
#define JSPAN (N / NSPLIT)   // 512
#define NCHUNK (JSPAN / KC)  // 8
#define ACC_STRIDE 64    // 48 dims + lsum@48 + pad
#define HSTR 49
#define RB 32            // rows per k_mlp block

typedef _Float16 half8 __attribute__((ext_vector_type(8)));
typedef float f32x4 __attribute__((ext_vector_type(4)));

// ---------------- Kernel 1a: Wh = x @ Wgat^T  [8192,128]x[48,128] -> [8192,48]
__global__ __launch_bounds__(256) void k_wh(const float* __restrict__ x,
                                            const float* __restrict__ Wg,
                                            float* __restrict__ Wh) {
    __shared__ float wT[DIN * DH];  // wT[k*DH + c] = Wg[c*DIN + k]
    int t = threadIdx.x;
    for (int e = t; e < DIN * DH; e += 256) {
        int c = e / DIN, k = e % DIN;
        wT[k * DH + c] = Wg[e];
    }
    __syncthreads();
    int o = blockIdx.x * 256 + t;
    int r = o / DH, c = o % DH;
    const float4* xr = (const float4*)(x + (size_t)r * DIN);
    float acc = 0.f;
    #pragma unroll 8
    for (int k4 = 0; k4 < DIN / 4; ++k4) {
        float4 xv = xr[k4];
        int kb = k4 * 4;
        acc += xv.x * wT[(kb + 0) * DH + c];
        acc += xv.y * wT[(kb + 1) * DH + c];
        acc += xv.z * wT[(kb + 2) * DH + c];
        acc += xv.w * wT[(kb + 3) * DH + c];
    }
    Wh[o] = acc;
}

// ---------------- Kernel 1b: s = Wh @ a^T
__global__ __launch_bounds__(256) void k_s(const float* __restrict__ Wh,
                                           const float* __restrict__ a,
                                           float* __restrict__ s) {
    int r = blockIdx.x * 256 + threadIdx.x;
    const float4* wr = (const float4*)(Wh + (size_t)r * DH);
    const float4* av = (const float4*)a;
    float acc = 0.f;
    #pragma unroll
    for (int k4 = 0; k4 < DH / 4; ++k4) {
        float4 w = wr[k4]; float4 aa = av[k4];
        acc += w.x * aa.x + w.y * aa.y + w.z * aa.z + w.w * aa.w;
    }
    s[r] = acc;
}

// ---------------- Kernel 1c: WhT16[c][r] = (f16)Wh[r][c]  (B operand source)
__global__ __launch_bounds__(256) void k_tr(const float* __restrict__ Wh,
                                            _Float16* __restrict__ WhT) {
    __shared__ _Float16 tile[DH][72];
    int t = threadIdx.x;
    int r0 = blockIdx.x * 64;
    for (int e = t; e < 64 * DH; e += 256) {
        int r = e / DH, c = e % DH;
        tile[c][r] = (_Float16)Wh[(size_t)(r0 + r) * DH + c];
    }
    __syncthreads();
    for (int u = t; u < DH * 8; u += 256) {
        int c = u >> 3, g = u & 7;
        *(half8*)&WhT[(size_t)c * N + r0 + g * 8] = *(const half8*)&tile[c][g * 8];
    }
}

// ---------------- Kernel 2: fused masked-softmax attention, f16 MFMA,
// software-pipelined. e = lrelu(s_i+s_j) bounded -> no max-subtraction;
// masked -> exact 0. Per block: 128 rows x 512 j (1 of 16 J-splits).
// Pipeline (1 barrier/chunk, dbuf pS+wS):
//   iter c: [issue adj(c+1)->regs] [phase A: p(c)->pS[buf]] barrier
//           [issue wS(c+1) loads] [MFMA(c)] [write wS(c+1)->LDS buf^1]
// adj register prefetch rides across the barrier (no vmcnt drain for
// plain reg loads); wS L2 loads hide under the MFMAs.
__global__ __launch_bounds__(256, 3) void k_gat(const int* __restrict__ adj,
                                                const _Float16* __restrict__ WhT,
                                                const float* __restrict__ s,
                                                float* __restrict__ accWs) {
    __shared__ _Float16 pS[2][MT][PSTR];   // A: P[row][j]
    __shared__ _Float16 wS[2][DH][PSTR];   // B^T: wS[d][j]
    __shared__ float sRow[MT];
    int t = threadIdx.x;
    int tile = blockIdx.x & 63;        // 64 row tiles of 128
    int split = blockIdx.x >> 6;       // 0..15
    int i0 = tile * MT;
    int jbase = split * JSPAN;

    if (t < MT) sRow[t] = s[i0 + t];

    int lane = t & 63, w = t >> 6;
    int ln16 = lane & 15, kq = lane >> 4;   // MFMA lane decomposition
    int jp = t & 31, rg = t >> 5;           // phase A: j-pair, 16-row group

    // constant B-frag, N-tile 3: col 48 = ones (softmax denom), rest 0
    half8 bc;
    {
        _Float16 v = (ln16 == 0) ? (_Float16)1.0f : (_Float16)0.0f;
        #pragma unroll
        for (int i = 0; i < 8; ++i) bc[i] = v;
    }

    f32x4 acc[2][4];
    #pragma unroll
    for (int m = 0; m < 2; ++m)
        #pragma unroll
        for (int n = 0; n < 4; ++n) acc[m][n] = (f32x4){0.f, 0.f, 0.f, 0.f};

    const int* arow = adj + (size_t)(i0 + rg * 16) * N + 2 * jp;

    // ---- preload chunk 0: adj -> regs, wS(0) -> LDS buf 0
    int2 av[16];
    #pragma unroll
    for (int it = 0; it < 16; ++it)
        av[it] = *(const int2*)(arow + (size_t)it * N + jbase);
    {
        int u0 = t;                        // 384 half8 segments: t and 256+t(<128)
        int row = u0 >> 3, s8 = u0 & 3 /*dummy init*/;
        s8 = u0 & 7;
        if (u0 < 384) { /* always true for t<256 */ }
        half8 v0 = *(const half8*)&WhT[(size_t)row * N + jbase + s8 * 8];
        *(half8*)&wS[0][row][s8 * 8] = v0;
        if (t < 128) {
            int u1 = 256 + t;
            int row1 = u1 >> 3, s81 = u1 & 7;
            half8 v1 = *(const half8*)&WhT[(size_t)row1 * N + jbase + s81 * 8];
            *(half8*)&wS[0][row1][s81 * 8] = v1;
        }
    }
    __syncthreads();

    int buf = 0;
    for (int chunk = 0; chunk < NCHUNK; ++chunk) {
        int j0 = jbase + chunk * KC;
        bool more = (chunk + 1 < NCHUNK);
        // ---- issue next chunk's adj loads (registers; in flight across barrier)
        int2 avn[16];
        if (more) {
            const int* ab = arow + (j0 + KC);
            #pragma unroll
            for (int it = 0; it < 16; ++it)
                avn[it] = *(const int2*)(ab + (size_t)it * N);
        }
        // ---- phase A: p (f16) for 128 rows x 64 j from current av
        {
            float2 sj = *(const float2*)(s + j0 + 2 * jp);
            #pragma unroll
            for (int it = 0; it < 16; ++it) {
                int r = rg * 16 + it;
                float e0 = sRow[r] + sj.x;
                float e1 = sRow[r] + sj.y;
                e0 = fmaxf(e0, 0.2f * e0);              // LeakyReLU(0.2)
                e1 = fmaxf(e1, 0.2f * e1);
                float p0 = av[it].x ? __expf(e0) : 0.f; // masked -> exact 0
                float p1 = av[it].y ? __expf(e1) : 0.f;
                union { _Float16 h[2]; unsigned u; } pk;
                pk.h[0] = (_Float16)p0;
                pk.h[1] = (_Float16)p1;
                *(unsigned*)&pS[buf][r][2 * jp] = pk.u;
            }
        }
        __syncthreads();
        // ---- issue wS(c+1) global loads (L2-resident WhT16; hide under MFMA)
        half8 wv0, wv1;
        int row0 = t >> 3, s80 = t & 7;
        int row1 = (256 + t) >> 3, s81 = t & 7;
        if (more) {
            int jn = j0 + KC;
            wv0 = *(const half8*)&WhT[(size_t)row0 * N + jn + s80 * 8];
            if (t < 128)
                wv1 = *(const half8*)&WhT[(size_t)row1 * N + jn + s81 * 8];
        }
        // ---- MFMA: wave w owns M-tiles 2w..2w+1; N-tiles 0..2 + ones col
        {
            int m0 = w * 32;
            #pragma unroll
            for (int kt = 0; kt < 2; ++kt) {
                int kk = kt * 32 + kq * 8;
                half8 b0 = *(const half8*)&wS[buf][0 + ln16][kk];
                half8 b1 = *(const half8*)&wS[buf][16 + ln16][kk];
                half8 b2 = *(const half8*)&wS[buf][32 + ln16][kk];
                #pragma unroll
                for (int mtl = 0; mtl < 2; ++mtl) {
                    half8 a = *(const half8*)&pS[buf][m0 + mtl * 16 + ln16][kk];
                    acc[mtl][0] = __builtin_amdgcn_mfma_f32_16x16x32_f16(a, b0, acc[mtl][0], 0, 0, 0);
                    acc[mtl][1] = __builtin_amdgcn_mfma_f32_16x16x32_f16(a, b1, acc[mtl][1], 0, 0, 0);
                    acc[mtl][2] = __builtin_amdgcn_mfma_f32_16x16x32_f16(a, b2, acc[mtl][2], 0, 0, 0);
                    acc[mtl][3] = __builtin_amdgcn_mfma_f32_16x16x32_f16(a, bc, acc[mtl][3], 0, 0, 0);
                }
            }
        }
        // ---- write wS(c+1) to the other buffer
        if (more) {
            *(half8*)&wS[buf ^ 1][row0][s80 * 8] = wv0;
            if (t < 128)
                *(half8*)&wS[buf ^ 1][row1][s81 * 8] = wv1;
        }
        // ---- rotate register pipeline
        #pragma unroll
        for (int it = 0; it < 16; ++it) av[it] = avn[it];
        buf ^= 1;
    }
    // ---- epilogue: C/D layout col=lane&15, row=kq*4+reg; per-split partials
    #pragma unroll
    for (int mtl = 0; mtl < 2; ++mtl) {
        size_t rbase = (size_t)split * N + i0 + w * 32 + mtl * 16 + kq * 4;
        #pragma unroll
        for (int nt = 0; nt < 4; ++nt) {
            int col = nt * 16 + ln16;
            if (nt == 3 && ln16 != 0) continue;   // only col 48 (lsum) useful
            #pragma unroll
            for (int reg = 0; reg < 4; ++reg)
                accWs[(rbase + reg) * ACC_STRIDE + col] = acc[mtl][nt][reg];
        }
    }
}

// ---------------- Kernel 3: reduce splits + LayerNorm + MLP 48->256->128->32
__global__ __launch_bounds__(256) void k_mlp(const float* __restrict__ accWs,
                                             const float* __restrict__ gamma,
                                             const float* __restrict__ beta,
                                             const float* __restrict__ W1, const float* __restrict__ b1,
                                             const float* __restrict__ W2, const float* __restrict__ b2,
                                             const float* __restrict__ W3, const float* __restrict__ b3,
                                             float* __restrict__ out) {
    __shared__ float hs[RB * HSTR];
    __shared__ float hN[RB * DH];
    __shared__ float h1[RB * 256];
    __shared__ float h2[RB * 128];
    int t = threadIdx.x;
    int r0 = blockIdx.x * RB;

    for (int e = t; e < RB * HSTR; e += 256) {
        int r = e / HSTR, d = e % HSTR;
        size_t base = (size_t)(r0 + r) * ACC_STRIDE + d;
        float v = 0.f;
        #pragma unroll
        for (int sp = 0; sp < NSPLIT; ++sp)
            v += accWs[(size_t)sp * N * ACC_STRIDE + base];
        hs[e] = v;
    }
    __syncthreads();

    // LayerNorm (two-pass), h' = acc / l
    if (t < RB) {
        float invl = 1.f / hs[t * HSTR + 48];
        float sum = 0.f;
        for (int d = 0; d < DH; ++d) sum += hs[t * HSTR + d];
        float mean = sum * invl * (1.f / DH);
        float var = 0.f;
        for (int d = 0; d < DH; ++d) {
            float dv = hs[t * HSTR + d] * invl - mean;
            var += dv * dv;
        }
        var *= (1.f / DH);
        float rs = rsqrtf(var + 1e-5f);
        for (int d = 0; d < DH; ++d) {
            float hv = (hs[t * HSTR + d] * invl - mean) * rs;
            hN[t * DH + d] = hv * gamma[d] + beta[d];
        }
    }
    __syncthreads();

    // MLP1: 48 -> 256; thread = 2 cols x 16 rows, W1 cols in VGPRs
    {
        int c0 = (t & 127) * 2, c1 = c0 + 1;
        int rbeg = (t >> 7) * 16;
        float4 wa[12], wb[12];
        const float4* wr0 = (const float4*)(W1 + c0 * DH);
        const float4* wr1 = (const float4*)(W1 + c1 * DH);
        #pragma unroll
        for (int k4 = 0; k4 < 12; ++k4) { wa[k4] = wr0[k4]; wb[k4] = wr1[k4]; }
        float ba = b1[c0], bb = b1[c1];
        for (int r = rbeg; r < rbeg + 16; ++r) {
            const float4* hv4 = (const float4*)&hN[r * DH];
            float a0 = ba, a1 = bb;
            #pragma unroll
            for (int k4 = 0; k4 < 12; ++k4) {
                float4 hv = hv4[k4];
                a0 += hv.x * wa[k4].x + hv.y * wa[k4].y + hv.z * wa[k4].z + hv.w * wa[k4].w;
                a1 += hv.x * wb[k4].x + hv.y * wb[k4].y + hv.z * wb[k4].z + hv.w * wb[k4].w;
            }
            h1[r * 256 + c0] = fmaxf(a0, 0.f);
            h1[r * 256 + c1] = fmaxf(a1, 0.f);
        }
    }
    __syncthreads();

    // MLP2: 256 -> 128; thread = 4 cols x 4 rows
    {
        int c4 = (t & 31) * 4;
        int rr0 = (t >> 5) * 4;
        float a[4][4];
        #pragma unroll
        for (int rr = 0; rr < 4; ++rr)
            #pragma unroll
            for (int cc = 0; cc < 4; ++cc) a[rr][cc] = 0.f;
        for (int k4 = 0; k4 < 64; ++k4) {
            float4 h[4], wv[4];
            #pragma unroll
            for (int rr = 0; rr < 4; ++rr)
                h[rr] = *(const float4*)&h1[(rr0 + rr) * 256 + 4 * k4];
            #pragma unroll
            for (int cc = 0; cc < 4; ++cc)
                wv[cc] = *(const float4*)&W2[(size_t)(c4 + cc) * 256 + 4 * k4];
            #pragma unroll
            for (int rr = 0; rr < 4; ++rr)
                #pragma unroll
                for (int cc = 0; cc < 4; ++cc)
                    a[rr][cc] += h[rr].x * wv[cc].x + h[rr].y * wv[cc].y
                               + h[rr].z * wv[cc].z + h[rr].w * wv[cc].w;
        }
        #pragma unroll
        for (int rr = 0; rr < 4; ++rr)
            #pragma unroll
            for (int cc = 0; cc < 4; ++cc)
                h2[(rr0 + rr) * 128 + c4 + cc] = fmaxf(a[rr][cc] + b2[c4 + cc], 0.f);
    }
    __syncthreads();

    // MLP3: 128 -> 32; thread = 1 col x 4 rows
    {
        int c = t & 31;
        int rr0 = (t >> 5) * 4;
        float a[4];
        float bias = b3[c];
        #pragma unroll
        for (int rr = 0; rr < 4; ++rr) a[rr] = bias;
        const float4* wrow = (const float4*)(W3 + c * 128);
        for (int k4 = 0; k4 < 32; ++k4) {
            float4 wv = wrow[k4];
            #pragma unroll
            for (int rr = 0; rr < 4; ++rr) {
                float4 hv = *(const float4*)&h2[(rr0 + rr) * 128 + 4 * k4];
                a[rr] += wv.x * hv.x + wv.y * hv.y + wv.z * hv.z + wv.w * hv.w;
            }
        }
        #pragma unroll
        for (int rr = 0; rr < 4; ++rr)
            out[(size_t)(r0 + rr0 + rr) * 32 + c] = a[rr];
    }
}

extern "C" void kernel_launch(void* const* d_in, const int* in_sizes, int n_in,
                              void* d_out, int out_size, void* d_ws, size_t ws_size,
                              hipStream_t stream) {
    const float* x     = (const float*)d_in[0];
    const int*   adj   = (const int*)d_in[1];
    const float* Wg    = (const float*)d_in[2];
    const float* a     = (const float*)d_in[3];
    const float* gamma = (const float*)d_in[4];
    const float* beta  = (const float*)d_in[5];
    const float* W1    = (const float*)d_in[6];
    const float* b1    = (const float*)d_in[7];
    const float* W2    = (const float*)d_in[8];
    const float* b2    = (const float*)d_in[9];
    const float* W3    = (const float*)d_in[10];
    const float* b3    = (const float*)d_in[11];
    float* out = (float*)d_out;

    float* ws = (float*)d_ws;
    float*     Wh    = ws;                                   // 393216 f32
    float*     s     = ws + (size_t)N * DH;                  // 8192 f32
    _Float16*  WhT   = (_Float16*)(ws + (size_t)N * DH + N); // 393216 f16
    float*     accWs = ws + (size_t)N * DH + N + (size_t)N * DH / 2; // 16*N*64 f32

    k_wh<<<N * DH / 256, 256, 0, stream>>>(x, Wg, Wh);
    k_s<<<N / 256, 256, 0, stream>>>(Wh, a, s);
    k_tr<<<N / 64, 256, 0, stream>>>(Wh, WhT);
    k_gat<<<64 * NSPLIT, 256, 0, stream>>>(adj, WhT, s, accWs);
    k_mlp<<<N / RB, 256, 0, stream>>>(accWs, gamma, beta, W1, b1, W2, b2, W3, b3, out);
}

// Round 6
// 480.563 us; speedup vs baseline: 1.0354x; 1.0023x over previous
//
#include <hip/hip_runtime.h>

#define N 8192
#define DIN 128
#define DH 48
#define MT 128           // rows per k_gat block (4 waves x 32 rows)
#define KC 64            // j-chunk
#define NSPLIT 16
#define JSPAN (N / NSPLIT)   // 512
#define NCHUNK (JSPAN / KC)  // 8
#define ACC_STRIDE 64    // 48 dims + lsum@48 + pad
#define HSTR 49
#define RB 32            // rows per k_mlp block

typedef _Float16 half8 __attribute__((ext_vector_type(8)));
typedef float f32x4 __attribute__((ext_vector_type(4)));

// ---------------- Kernel 1a: Wh = x @ Wgat^T  [8192,128]x[48,128] -> [8192,48]
__global__ __launch_bounds__(256) void k_wh(const float* __restrict__ x,
                                            const float* __restrict__ Wg,
                                            float* __restrict__ Wh) {
    __shared__ float wT[DIN * DH];  // wT[k*DH + c] = Wg[c*DIN + k]
    int t = threadIdx.x;
    for (int e = t; e < DIN * DH; e += 256) {
        int c = e / DIN, k = e % DIN;
        wT[k * DH + c] = Wg[e];
    }
    __syncthreads();
    int o = blockIdx.x * 256 + t;
    int r = o / DH, c = o % DH;
    const float4* xr = (const float4*)(x + (size_t)r * DIN);
    float acc = 0.f;
    #pragma unroll 8
    for (int k4 = 0; k4 < DIN / 4; ++k4) {
        float4 xv = xr[k4];
        int kb = k4 * 4;
        acc += xv.x * wT[(kb + 0) * DH + c];
        acc += xv.y * wT[(kb + 1) * DH + c];
        acc += xv.z * wT[(kb + 2) * DH + c];
        acc += xv.w * wT[(kb + 3) * DH + c];
    }
    Wh[o] = acc;
}

// ---------------- Kernel 1b: s = Wh @ a^T
__global__ __launch_bounds__(256) void k_s(const float* __restrict__ Wh,
                                           const float* __restrict__ a,
                                           float* __restrict__ s) {
    int r = blockIdx.x * 256 + threadIdx.x;
    const float4* wr = (const float4*)(Wh + (size_t)r * DH);
    const float4* av = (const float4*)a;
    float acc = 0.f;
    #pragma unroll
    for (int k4 = 0; k4 < DH / 4; ++k4) {
        float4 w = wr[k4]; float4 aa = av[k4];
        acc += w.x * aa.x + w.y * aa.y + w.z * aa.z + w.w * aa.w;
    }
    s[r] = acc;
}

// ---------------- Kernel 1c: WhT16[c][r] = (f16)Wh[r][c]  (B operand source)
__global__ __launch_bounds__(256) void k_tr(const float* __restrict__ Wh,
                                            _Float16* __restrict__ WhT) {
    __shared__ _Float16 tile[DH][72];
    int t = threadIdx.x;
    int r0 = blockIdx.x * 64;
    for (int e = t; e < 64 * DH; e += 256) {
        int r = e / DH, c = e % DH;
        tile[c][r] = (_Float16)Wh[(size_t)(r0 + r) * DH + c];
    }
    __syncthreads();
    for (int u = t; u < DH * 8; u += 256) {
        int c = u >> 3, g = u & 7;
        *(half8*)&WhT[(size_t)c * N + r0 + g * 8] = *(const half8*)&tile[c][g * 8];
    }
}

// p helper: 8 masked-softmax numerator values, f16-packed
__device__ inline half8 mk_p(float si, float4 sa, float4 sb, int4 m0, int4 m1) {
    float e0 = si + sa.x, e1 = si + sa.y, e2 = si + sa.z, e3 = si + sa.w;
    float e4 = si + sb.x, e5 = si + sb.y, e6 = si + sb.z, e7 = si + sb.w;
    e0 = fmaxf(e0, 0.2f * e0); e1 = fmaxf(e1, 0.2f * e1);
    e2 = fmaxf(e2, 0.2f * e2); e3 = fmaxf(e3, 0.2f * e3);
    e4 = fmaxf(e4, 0.2f * e4); e5 = fmaxf(e5, 0.2f * e5);
    e6 = fmaxf(e6, 0.2f * e6); e7 = fmaxf(e7, 0.2f * e7);
    half8 r;
    r[0] = (_Float16)(m0.x ? __expf(e0) : 0.f);
    r[1] = (_Float16)(m0.y ? __expf(e1) : 0.f);
    r[2] = (_Float16)(m0.z ? __expf(e2) : 0.f);
    r[3] = (_Float16)(m0.w ? __expf(e3) : 0.f);
    r[4] = (_Float16)(m1.x ? __expf(e4) : 0.f);
    r[5] = (_Float16)(m1.y ? __expf(e5) : 0.f);
    r[6] = (_Float16)(m1.z ? __expf(e6) : 0.f);
    r[7] = (_Float16)(m1.w ? __expf(e7) : 0.f);
    return r;
}

// ---------------- Kernel 2: fused masked-softmax attention, f16 MFMA,
// ZERO LDS / ZERO barriers. Each thread computes its A-fragment p-values
// directly in registers (A[m=lane&15][k=(lane>>4)*8+j] -> one row x 8
// consecutive j per (mtl,kt)), loading its own adj words (2x int4, full
// cache-line utilization across the 16 lanes). B-frags gathered from
// L2-resident WhT (48 KB working set per split, reused by 64 blocks).
// Softmax denominator = constant ones-column B-frag (N-tile 3, col 48).
// No __syncthreads -> no vmcnt drains; waves free-run and overlap chunk
// c+1 loads with chunk c compute via hardware scoreboarding.
__global__ __launch_bounds__(256, 4) void k_gat(const int* __restrict__ adj,
                                                const _Float16* __restrict__ WhT,
                                                const float* __restrict__ s,
                                                float* __restrict__ accWs) {
    int t = threadIdx.x;
    int tile = blockIdx.x & 63;        // 64 row tiles of 128
    int split = blockIdx.x >> 6;       // 0..15
    int i0 = tile * MT;
    int jbase = split * JSPAN;

    int lane = t & 63, w = t >> 6;
    int ln16 = lane & 15, kq = lane >> 4;   // MFMA lane decomposition

    // constant B-frag, N-tile 3: col 48 = ones (softmax denom), rest 0
    half8 bc;
    {
        _Float16 v = (ln16 == 0) ? (_Float16)1.0f : (_Float16)0.0f;
        #pragma unroll
        for (int i = 0; i < 8; ++i) bc[i] = v;
    }

    f32x4 acc[2][4];
    #pragma unroll
    for (int m = 0; m < 2; ++m)
        #pragma unroll
        for (int n = 0; n < 4; ++n) acc[m][n] = (f32x4){0.f, 0.f, 0.f, 0.f};

    const int row0 = i0 + w * 32 + ln16;     // mtl=0 row
    const int row1 = row0 + 16;              // mtl=1 row
    const float si0 = s[row0];
    const float si1 = s[row1];
    const int* ar0 = adj + (size_t)row0 * N;
    const int* ar1 = adj + (size_t)row1 * N;

    for (int chunk = 0; chunk < NCHUNK; ++chunk) {
        const int j0 = jbase + chunk * KC;
        const int jk0 = j0 + kq * 8;         // kt=0 k-segment
        const int jk1 = jk0 + 32;            // kt=1 k-segment

        // ---- issue all chunk loads (18 vmem, independent)
        int4 m00a = *(const int4*)(ar0 + jk0);
        int4 m00b = *(const int4*)(ar0 + jk0 + 4);
        int4 m01a = *(const int4*)(ar0 + jk1);
        int4 m01b = *(const int4*)(ar0 + jk1 + 4);
        int4 m10a = *(const int4*)(ar1 + jk0);
        int4 m10b = *(const int4*)(ar1 + jk0 + 4);
        int4 m11a = *(const int4*)(ar1 + jk1);
        int4 m11b = *(const int4*)(ar1 + jk1 + 4);
        float4 s0a = *(const float4*)(s + jk0);
        float4 s0b = *(const float4*)(s + jk0 + 4);
        float4 s1a = *(const float4*)(s + jk1);
        float4 s1b = *(const float4*)(s + jk1 + 4);
        half8 bf00 = *(const half8*)&WhT[(size_t)(0  + ln16) * N + jk0];
        half8 bf01 = *(const half8*)&WhT[(size_t)(16 + ln16) * N + jk0];
        half8 bf02 = *(const half8*)&WhT[(size_t)(32 + ln16) * N + jk0];
        half8 bf10 = *(const half8*)&WhT[(size_t)(0  + ln16) * N + jk1];
        half8 bf11 = *(const half8*)&WhT[(size_t)(16 + ln16) * N + jk1];
        half8 bf12 = *(const half8*)&WhT[(size_t)(32 + ln16) * N + jk1];

        // ---- A-frags in registers (p never touches LDS)
        half8 a00 = mk_p(si0, s0a, s0b, m00a, m00b);   // row0, kt0
        half8 a01 = mk_p(si0, s1a, s1b, m01a, m01b);   // row0, kt1
        half8 a10 = mk_p(si1, s0a, s0b, m10a, m10b);   // row1, kt0
        half8 a11 = mk_p(si1, s1a, s1b, m11a, m11b);   // row1, kt1

        // ---- MFMAs: kt0 then kt1
        acc[0][0] = __builtin_amdgcn_mfma_f32_16x16x32_f16(a00, bf00, acc[0][0], 0, 0, 0);
        acc[0][1] = __builtin_amdgcn_mfma_f32_16x16x32_f16(a00, bf01, acc[0][1], 0, 0, 0);
        acc[0][2] = __builtin_amdgcn_mfma_f32_16x16x32_f16(a00, bf02, acc[0][2], 0, 0, 0);
        acc[0][3] = __builtin_amdgcn_mfma_f32_16x16x32_f16(a00, bc,   acc[0][3], 0, 0, 0);
        acc[1][0] = __builtin_amdgcn_mfma_f32_16x16x32_f16(a10, bf00, acc[1][0], 0, 0, 0);
        acc[1][1] = __builtin_amdgcn_mfma_f32_16x16x32_f16(a10, bf01, acc[1][1], 0, 0, 0);
        acc[1][2] = __builtin_amdgcn_mfma_f32_16x16x32_f16(a10, bf02, acc[1][2], 0, 0, 0);
        acc[1][3] = __builtin_amdgcn_mfma_f32_16x16x32_f16(a10, bc,   acc[1][3], 0, 0, 0);
        acc[0][0] = __builtin_amdgcn_mfma_f32_16x16x32_f16(a01, bf10, acc[0][0], 0, 0, 0);
        acc[0][1] = __builtin_amdgcn_mfma_f32_16x16x32_f16(a01, bf11, acc[0][1], 0, 0, 0);
        acc[0][2] = __builtin_amdgcn_mfma_f32_16x16x32_f16(a01, bf12, acc[0][2], 0, 0, 0);
        acc[0][3] = __builtin_amdgcn_mfma_f32_16x16x32_f16(a01, bc,   acc[0][3], 0, 0, 0);
        acc[1][0] = __builtin_amdgcn_mfma_f32_16x16x32_f16(a11, bf10, acc[1][0], 0, 0, 0);
        acc[1][1] = __builtin_amdgcn_mfma_f32_16x16x32_f16(a11, bf11, acc[1][1], 0, 0, 0);
        acc[1][2] = __builtin_amdgcn_mfma_f32_16x16x32_f16(a11, bf12, acc[1][2], 0, 0, 0);
        acc[1][3] = __builtin_amdgcn_mfma_f32_16x16x32_f16(a11, bc,   acc[1][3], 0, 0, 0);
    }

    // ---- epilogue: C/D layout col=lane&15, row=kq*4+reg; per-split partials
    #pragma unroll
    for (int mtl = 0; mtl < 2; ++mtl) {
        size_t rbase = (size_t)split * N + i0 + w * 32 + mtl * 16 + kq * 4;
        #pragma unroll
        for (int nt = 0; nt < 4; ++nt) {
            int col = nt * 16 + ln16;
            if (nt == 3 && ln16 != 0) continue;   // only col 48 (lsum) useful
            #pragma unroll
            for (int reg = 0; reg < 4; ++reg)
                accWs[(rbase + reg) * ACC_STRIDE + col] = acc[mtl][nt][reg];
        }
    }
}

// ---------------- Kernel 3: reduce splits + LayerNorm + MLP 48->256->128->32
__global__ __launch_bounds__(256) void k_mlp(const float* __restrict__ accWs,
                                             const float* __restrict__ gamma,
                                             const float* __restrict__ beta,
                                             const float* __restrict__ W1, const float* __restrict__ b1,
                                             const float* __restrict__ W2, const float* __restrict__ b2,
                                             const float* __restrict__ W3, const float* __restrict__ b3,
                                             float* __restrict__ out) {
    __shared__ float hs[RB * HSTR];
    __shared__ float hN[RB * DH];
    __shared__ float h1[RB * 256];
    __shared__ float h2[RB * 128];
    int t = threadIdx.x;
    int r0 = blockIdx.x * RB;

    for (int e = t; e < RB * HSTR; e += 256) {
        int r = e / HSTR, d = e % HSTR;
        size_t base = (size_t)(r0 + r) * ACC_STRIDE + d;
        float v = 0.f;
        #pragma unroll
        for (int sp = 0; sp < NSPLIT; ++sp)
            v += accWs[(size_t)sp * N * ACC_STRIDE + base];
        hs[e] = v;
    }
    __syncthreads();

    // LayerNorm (two-pass), h' = acc / l
    if (t < RB) {
        float invl = 1.f / hs[t * HSTR + 48];
        float sum = 0.f;
        for (int d = 0; d < DH; ++d) sum += hs[t * HSTR + d];
        float mean = sum * invl * (1.f / DH);
        float var = 0.f;
        for (int d = 0; d < DH; ++d) {
            float dv = hs[t * HSTR + d] * invl - mean;
            var += dv * dv;
        }
        var *= (1.f / DH);
        float rs = rsqrtf(var + 1e-5f);
        for (int d = 0; d < DH; ++d) {
            float hv = (hs[t * HSTR + d] * invl - mean) * rs;
            hN[t * DH + d] = hv * gamma[d] + beta[d];
        }
    }
    __syncthreads();

    // MLP1: 48 -> 256; thread = 2 cols x 16 rows, W1 cols in VGPRs
    {
        int c0 = (t & 127) * 2, c1 = c0 + 1;
        int rbeg = (t >> 7) * 16;
        float4 wa[12], wb[12];
        const float4* wr0 = (const float4*)(W1 + c0 * DH);
        const float4* wr1 = (const float4*)(W1 + c1 * DH);
        #pragma unroll
        for (int k4 = 0; k4 < 12; ++k4) { wa[k4] = wr0[k4]; wb[k4] = wr1[k4]; }
        float ba = b1[c0], bb = b1[c1];
        for (int r = rbeg; r < rbeg + 16; ++r) {
            const float4* hv4 = (const float4*)&hN[r * DH];
            float a0 = ba, a1 = bb;
            #pragma unroll
            for (int k4 = 0; k4 < 12; ++k4) {
                float4 hv = hv4[k4];
                a0 += hv.x * wa[k4].x + hv.y * wa[k4].y + hv.z * wa[k4].z + hv.w * wa[k4].w;
                a1 += hv.x * wb[k4].x + hv.y * wb[k4].y + hv.z * wb[k4].z + hv.w * wb[k4].w;
            }
            h1[r * 256 + c0] = fmaxf(a0, 0.f);
            h1[r * 256 + c1] = fmaxf(a1, 0.f);
        }
    }
    __syncthreads();

    // MLP2: 256 -> 128; thread = 4 cols x 4 rows
    {
        int c4 = (t & 31) * 4;
        int rr0 = (t >> 5) * 4;
        float a[4][4];
        #pragma unroll
        for (int rr = 0; rr < 4; ++rr)
            #pragma unroll
            for (int cc = 0; cc < 4; ++cc) a[rr][cc] = 0.f;
        for (int k4 = 0; k4 < 64; ++k4) {
            float4 h[4], wv[4];
            #pragma unroll
            for (int rr = 0; rr < 4; ++rr)
                h[rr] = *(const float4*)&h1[(rr0 + rr) * 256 + 4 * k4];
            #pragma unroll
            for (int cc = 0; cc < 4; ++cc)
                wv[cc] = *(const float4*)&W2[(size_t)(c4 + cc) * 256 + 4 * k4];
            #pragma unroll
            for (int rr = 0; rr < 4; ++rr)
                #pragma unroll
                for (int cc = 0; cc < 4; ++cc)
                    a[rr][cc] += h[rr].x * wv[cc].x + h[rr].y * wv[cc].y
                               + h[rr].z * wv[cc].z + h[rr].w * wv[cc].w;
        }
        #pragma unroll
        for (int rr = 0; rr < 4; ++rr)
            #pragma unroll
            for (int cc = 0; cc < 4; ++cc)
                h2[(rr0 + rr) * 128 + c4 + cc] = fmaxf(a[rr][cc] + b2[c4 + cc], 0.f);
    }
    __syncthreads();

    // MLP3: 128 -> 32; thread = 1 col x 4 rows
    {
        int c = t & 31;
        int rr0 = (t >> 5) * 4;
        float a[4];
        float bias = b3[c];
        #pragma unroll
        for (int rr = 0; rr < 4; ++rr) a[rr] = bias;
        const float4* wrow = (const float4*)(W3 + c * 128);
        for (int k4 = 0; k4 < 32; ++k4) {
            float4 wv = wrow[k4];
            #pragma unroll
            for (int rr = 0; rr < 4; ++rr) {
                float4 hv = *(const float4*)&h2[(rr0 + rr) * 128 + 4 * k4];
                a[rr] += wv.x * hv.x + wv.y * hv.y + wv.z * hv.z + wv.w * hv.w;
            }
        }
        #pragma unroll
        for (int rr = 0; rr < 4; ++rr)
            out[(size_t)(r0 + rr0 + rr) * 32 + c] = a[rr];
    }
}

extern "C" void kernel_launch(void* const* d_in, const int* in_sizes, int n_in,
                              void* d_out, int out_size, void* d_ws, size_t ws_size,
                              hipStream_t stream) {
    const float* x     = (const float*)d_in[0];
    const int*   adj   = (const int*)d_in[1];
    const float* Wg    = (const float*)d_in[2];
    const float* a     = (const float*)d_in[3];
    const float* gamma = (const float*)d_in[4];
    const float* beta  = (const float*)d_in[5];
    const float* W1    = (const float*)d_in[6];
    const float* b1    = (const float*)d_in[7];
    const float* W2    = (const float*)d_in[8];
    const float* b2    = (const float*)d_in[9];
    const float* W3    = (const float*)d_in[10];
    const float* b3    = (const float*)d_in[11];
    float* out = (float*)d_out;

    float* ws = (float*)d_ws;
    float*     Wh    = ws;                                   // 393216 f32
    float*     s     = ws + (size_t)N * DH;                  // 8192 f32
    _Float16*  WhT   = (_Float16*)(ws + (size_t)N * DH + N); // 393216 f16
    float*     accWs = ws + (size_t)N * DH + N + (size_t)N * DH / 2; // 16*N*64 f32

    k_wh<<<N * DH / 256, 256, 0, stream>>>(x, Wg, Wh);
    k_s<<<N / 256, 256, 0, stream>>>(Wh, a, s);
    k_tr<<<N / 64, 256, 0, stream>>>(Wh, WhT);
    k_gat<<<64 * NSPLIT, 256, 0, stream>>>(adj, WhT, s, accWs);
    k_mlp<<<N / RB, 256, 0, stream>>>(accWs, gamma, beta, W1, b1, W2, b2, W3, b3, out);
}